// Round 5
// baseline (401.704 us; speedup 1.0000x reference)
//
#include <hip/hip_runtime.h>
#include <math.h>

#define D_DIM 1024
#define H_DIM 4096
#define R_DIM 64
#define S_SP  4
#define NTOK  8192
#define CHUNK 1024   // H/S

// ---------------- K0: transpose W2 (D,H) -> W2T (H,D) ----------------
__global__ __launch_bounds__(256) void k_transpose(const float* __restrict__ W2,
                                                   float* __restrict__ W2T) {
  __shared__ float tile[64][65];
  const int hb = blockIdx.x * 64, db = blockIdx.y * 64;
  const int tx = threadIdx.x & 63, ty = threadIdx.x >> 6;
#pragma unroll
  for (int r = 0; r < 16; ++r) {
    const int d = ty * 16 + r;
    tile[tx][d] = W2[(size_t)(db + d) * H_DIM + hb + tx];
  }
  __syncthreads();
#pragma unroll
  for (int r = 0; r < 16; ++r) {
    const int h = ty * 16 + r;
    W2T[(size_t)(hb + h) * D_DIM + db + tx] = tile[h][tx];
  }
}

// force a pointer to be treated as wave-uniform (SGPR) -> scalar loads
__device__ __forceinline__ const float* uniform_ptr(const float* p) {
  unsigned long long u = (unsigned long long)p;
  unsigned int lo = __builtin_amdgcn_readfirstlane((unsigned int)u);
  unsigned int hi = __builtin_amdgcn_readfirstlane((unsigned int)(u >> 32));
  return (const float*)(((unsigned long long)hi << 32) | lo);
}

// ---------------- K1: ch = relu(x @ Wc1^T + bc1)  (8192x64, K=1024) ----
// x rows forced wave-uniform -> s_load broadcast (scalar pipe, free for VALU);
// Wc1 chunks per-lane VMEM; fully static offsets inside each c-iteration.
#define K1_TOK 16
__global__ __launch_bounds__(256, 4) void k_ctrl(const float* __restrict__ x,
                                                 const float* __restrict__ Wc1,
                                                 const float* __restrict__ bc1,
                                                 float* __restrict__ ch) {
  const int tid = threadIdx.x;
  const int tok0 = blockIdx.x * K1_TOK;
  const int r = tid & 63;   // output column r (R=64)
  const int g = tid >> 6;   // token group 0..3 (4 tokens each, wave-uniform)
  const float* xrow0 = uniform_ptr(x + (size_t)(tok0 + g * 4 + 0) * D_DIM);
  const float* xrow1 = uniform_ptr(x + (size_t)(tok0 + g * 4 + 1) * D_DIM);
  const float* xrow2 = uniform_ptr(x + (size_t)(tok0 + g * 4 + 2) * D_DIM);
  const float* xrow3 = uniform_ptr(x + (size_t)(tok0 + g * 4 + 3) * D_DIM);
  const float* wbase = Wc1 + (size_t)r * D_DIM;
  float acc[4] = {0.f, 0.f, 0.f, 0.f};
#pragma unroll 1
  for (int c = 0; c < 64; ++c) {      // 16-float chunks of the K dim
    const int k0 = c * 16;
    const float4 w0 = *(const float4*)(wbase + k0 + 0);
    const float4 w1 = *(const float4*)(wbase + k0 + 4);
    const float4 w2 = *(const float4*)(wbase + k0 + 8);
    const float4 w3 = *(const float4*)(wbase + k0 + 12);
    const float* xr[4] = {xrow0 + k0, xrow1 + k0, xrow2 + k0, xrow3 + k0};
#pragma unroll
    for (int t = 0; t < 4; ++t) {
      const float4 c0 = *(const float4*)(xr[t] + 0);
      const float4 c1 = *(const float4*)(xr[t] + 4);
      const float4 c2 = *(const float4*)(xr[t] + 8);
      const float4 c3 = *(const float4*)(xr[t] + 12);
      float a = acc[t];
      a = fmaf(c0.x, w0.x, a); a = fmaf(c0.y, w0.y, a);
      a = fmaf(c0.z, w0.z, a); a = fmaf(c0.w, w0.w, a);
      a = fmaf(c1.x, w1.x, a); a = fmaf(c1.y, w1.y, a);
      a = fmaf(c1.z, w1.z, a); a = fmaf(c1.w, w1.w, a);
      a = fmaf(c2.x, w2.x, a); a = fmaf(c2.y, w2.y, a);
      a = fmaf(c2.z, w2.z, a); a = fmaf(c2.w, w2.w, a);
      a = fmaf(c3.x, w3.x, a); a = fmaf(c3.y, w3.y, a);
      a = fmaf(c3.z, w3.z, a); a = fmaf(c3.w, w3.w, a);
      acc[t] = a;
    }
    __builtin_amdgcn_sched_barrier(0);
  }
#pragma unroll
  for (int t = 0; t < 4; ++t) {
    const float v = acc[t] + bc1[r];
    ch[(size_t)(tok0 + g * 4 + t) * R_DIM + r] = v > 0.f ? v : 0.f;
  }
}

// ------- K2: logits = ch @ Wc2^T + bc2 (+gumbel), per-chunk argmax ------
// Fully-unrolled kk (static offsets -> offset: immediates) with
// sched_barrier(0) fences between kk sub-blocks to bound the live set.
#define K2_TOK 16

#define KK_BLOCK(KKC) do {                                                  \
    const float4 w0 = *(const float4*)(wrow + (KKC) * 16 + 0);              \
    const float4 w1 = *(const float4*)(wrow + (KKC) * 16 + 4);              \
    const float4 w2 = *(const float4*)(wrow + (KKC) * 16 + 8);              \
    const float4 w3 = *(const float4*)(wrow + (KKC) * 16 + 12);             \
    _Pragma("unroll")                                                       \
    for (int t = 0; t < K2_TOK; ++t) {                                      \
      const float* cp = cb + t * 64 + (KKC) * 16;                           \
      const float4 c0 = *(const float4*)(cp + 0);                           \
      const float4 c1 = *(const float4*)(cp + 4);                           \
      const float4 c2 = *(const float4*)(cp + 8);                           \
      const float4 c3 = *(const float4*)(cp + 12);                          \
      float a = acc[t];                                                     \
      a = fmaf(c0.x, w0.x, a); a = fmaf(c0.y, w0.y, a);                     \
      a = fmaf(c0.z, w0.z, a); a = fmaf(c0.w, w0.w, a);                     \
      a = fmaf(c1.x, w1.x, a); a = fmaf(c1.y, w1.y, a);                     \
      a = fmaf(c1.z, w1.z, a); a = fmaf(c1.w, w1.w, a);                     \
      a = fmaf(c2.x, w2.x, a); a = fmaf(c2.y, w2.y, a);                     \
      a = fmaf(c2.z, w2.z, a); a = fmaf(c2.w, w2.w, a);                     \
      a = fmaf(c3.x, w3.x, a); a = fmaf(c3.y, w3.y, a);                     \
      a = fmaf(c3.z, w3.z, a); a = fmaf(c3.w, w3.w, a);                     \
      acc[t] = a;                                                           \
    }                                                                       \
    __builtin_amdgcn_sched_barrier(0);                                      \
  } while (0)

__global__ __launch_bounds__(256, 4) void k_gate(const float* __restrict__ ch,
                                                 const float* __restrict__ Wc2,
                                                 const float* __restrict__ bc2,
                                                 const float* __restrict__ gumbel,
                                                 int* __restrict__ idx) {
  __shared__ float redv[4][K2_TOK];
  __shared__ int   redi[4][K2_TOK];
  const int tid = threadIdx.x;
  const int tok0 = blockIdx.x * K2_TOK;
  const int s = blockIdx.y;
  const float* cb = ch + (size_t)tok0 * R_DIM;   // block-uniform base -> s_load
  float bv[K2_TOK];
  int   bi[K2_TOK];
#pragma unroll
  for (int t = 0; t < K2_TOK; ++t) { bv[t] = -INFINITY; bi[t] = 0; }
#pragma unroll 1
  for (int hi = 0; hi < 4; ++hi) {
    const int hloc = hi * 256 + tid;              // h within chunk, 0..1023
    const float* wrow = Wc2 + (size_t)(s * CHUNK + hloc) * R_DIM;
    const float* gp = gumbel + ((size_t)tok0 * 4 + s) * CHUNK + hloc;
    // issue gumbel loads early; HBM latency hides under the FMA blocks
    float gum[K2_TOK];
#pragma unroll
    for (int t = 0; t < K2_TOK; ++t) gum[t] = gp[(size_t)t * 4 * CHUNK];
    float acc[K2_TOK];
#pragma unroll
    for (int t = 0; t < K2_TOK; ++t) acc[t] = 0.f;
    KK_BLOCK(0);
    KK_BLOCK(1);
    KK_BLOCK(2);
    KK_BLOCK(3);
    const float bias = bc2[s * CHUNK + hloc];
#pragma unroll
    for (int t = 0; t < K2_TOK; ++t) {
      const float val = acc[t] + bias + gum[t];
      if (val > bv[t] || (val == bv[t] && hloc < bi[t])) { bv[t] = val; bi[t] = hloc; }
    }
  }
  // argmax reduce: wave shuffle, then cross-wave via LDS
#pragma unroll
  for (int t = 0; t < K2_TOK; ++t) {
    float v = bv[t];
    int ii = bi[t];
#pragma unroll
    for (int o = 32; o > 0; o >>= 1) {
      const float ov = __shfl_down(v, o);
      const int   oi = __shfl_down(ii, o);
      if (ov > v || (ov == v && oi < ii)) { v = ov; ii = oi; }
    }
    if ((tid & 63) == 0) { redv[tid >> 6][t] = v; redi[tid >> 6][t] = ii; }
  }
  __syncthreads();
  if (tid < K2_TOK) {
    float v = redv[0][tid];
    int ii = redi[0][tid];
#pragma unroll
    for (int wv = 1; wv < 4; ++wv) {
      const float ov = redv[wv][tid];
      const int   oi = redi[wv][tid];
      if (ov > v || (ov == v && oi < ii)) { v = ov; ii = oi; }
    }
    idx[(size_t)(tok0 + tid) * S_SP + s] = s * CHUNK + ii;
  }
}

// ------- K3: wave-per-token sparse FFN (4 tokens/block, no syncthreads) ---
__global__ __launch_bounds__(256) void k_ffn(const float* __restrict__ x,
                                             const float* __restrict__ W1,
                                             const float* __restrict__ b1,
                                             const float* __restrict__ W2T,
                                             const float* __restrict__ b2,
                                             const int* __restrict__ idx,
                                             float* __restrict__ out) {
  const int tid  = threadIdx.x;
  const int lane = tid & 63;
  const int wv   = tid >> 6;
  const int token = blockIdx.x * 4 + wv;
  const int4 h4 = *(const int4*)(idx + (size_t)token * S_SP);
  const int h[4] = {h4.x, h4.y, h4.z, h4.w};
  const int d0 = lane * 16;
  const float* xp = x + (size_t)token * D_DIM + d0;
  const float4 x0 = *(const float4*)(xp + 0);
  const float4 x1 = *(const float4*)(xp + 4);
  const float4 x2 = *(const float4*)(xp + 8);
  const float4 x3 = *(const float4*)(xp + 12);
  float p[4];
#pragma unroll
  for (int s2 = 0; s2 < 4; ++s2) {
    const float* wr = W1 + (size_t)h[s2] * D_DIM + d0;
    const float4 a0 = *(const float4*)(wr + 0);
    const float4 a1 = *(const float4*)(wr + 4);
    const float4 a2 = *(const float4*)(wr + 8);
    const float4 a3 = *(const float4*)(wr + 12);
    float v = 0.f;
    v = fmaf(x0.x, a0.x, v); v = fmaf(x0.y, a0.y, v);
    v = fmaf(x0.z, a0.z, v); v = fmaf(x0.w, a0.w, v);
    v = fmaf(x1.x, a1.x, v); v = fmaf(x1.y, a1.y, v);
    v = fmaf(x1.z, a1.z, v); v = fmaf(x1.w, a1.w, v);
    v = fmaf(x2.x, a2.x, v); v = fmaf(x2.y, a2.y, v);
    v = fmaf(x2.z, a2.z, v); v = fmaf(x2.w, a2.w, v);
    v = fmaf(x3.x, a3.x, v); v = fmaf(x3.y, a3.y, v);
    v = fmaf(x3.z, a3.z, v); v = fmaf(x3.w, a3.w, v);
    p[s2] = v;
  }
  // butterfly reduce across the wave: every lane ends with the full dot
#pragma unroll
  for (int s2 = 0; s2 < 4; ++s2) {
#pragma unroll
    for (int o = 1; o < 64; o <<= 1) p[s2] += __shfl_xor(p[s2], o);
  }
  float hvv[4];
#pragma unroll
  for (int s2 = 0; s2 < 4; ++s2) {
    const float v = p[s2] + b1[h[s2]];
    hvv[s2] = v > 0.f ? v : 0.f;
  }
  float4 o0 = *(const float4*)(b2 + d0 + 0);
  float4 o1 = *(const float4*)(b2 + d0 + 4);
  float4 o2 = *(const float4*)(b2 + d0 + 8);
  float4 o3 = *(const float4*)(b2 + d0 + 12);
#pragma unroll
  for (int s2 = 0; s2 < 4; ++s2) {
    const float* wr = W2T + (size_t)h[s2] * D_DIM + d0;
    const float4 a0 = *(const float4*)(wr + 0);
    const float4 a1 = *(const float4*)(wr + 4);
    const float4 a2 = *(const float4*)(wr + 8);
    const float4 a3 = *(const float4*)(wr + 12);
    const float g = hvv[s2];
    o0.x = fmaf(g, a0.x, o0.x); o0.y = fmaf(g, a0.y, o0.y);
    o0.z = fmaf(g, a0.z, o0.z); o0.w = fmaf(g, a0.w, o0.w);
    o1.x = fmaf(g, a1.x, o1.x); o1.y = fmaf(g, a1.y, o1.y);
    o1.z = fmaf(g, a1.z, o1.z); o1.w = fmaf(g, a1.w, o1.w);
    o2.x = fmaf(g, a2.x, o2.x); o2.y = fmaf(g, a2.y, o2.y);
    o2.z = fmaf(g, a2.z, o2.z); o2.w = fmaf(g, a2.w, o2.w);
    o3.x = fmaf(g, a3.x, o3.x); o3.y = fmaf(g, a3.y, o3.y);
    o3.z = fmaf(g, a3.z, o3.z); o3.w = fmaf(g, a3.w, o3.w);
  }
  float* op = out + (size_t)token * D_DIM + d0;
  *(float4*)(op + 0)  = o0;
  *(float4*)(op + 4)  = o1;
  *(float4*)(op + 8)  = o2;
  *(float4*)(op + 12) = o3;
}

extern "C" void kernel_launch(void* const* d_in, const int* in_sizes, int n_in,
                              void* d_out, int out_size, void* d_ws, size_t ws_size,
                              hipStream_t stream) {
  const float* x      = (const float*)d_in[0];
  const float* W1     = (const float*)d_in[1];
  const float* b1     = (const float*)d_in[2];
  const float* W2     = (const float*)d_in[3];
  const float* b2     = (const float*)d_in[4];
  const float* Wc1    = (const float*)d_in[5];
  const float* bc1    = (const float*)d_in[6];
  const float* Wc2    = (const float*)d_in[7];
  const float* bc2    = (const float*)d_in[8];
  const float* gumbel = (const float*)d_in[9];
  float* out = (float*)d_out;

  char* ws = (char*)d_ws;
  float* W2T = (float*)ws;                                           // 16.78 MB
  float* ch  = (float*)(ws + (size_t)H_DIM * D_DIM * 4);             //  2.10 MB
  int*   idx = (int*)(ws + (size_t)H_DIM * D_DIM * 4
                         + (size_t)NTOK * R_DIM * 4);                //  0.13 MB

  hipLaunchKernelGGL(k_transpose, dim3(H_DIM / 64, D_DIM / 64), dim3(256), 0, stream,
                     W2, W2T);
  hipLaunchKernelGGL(k_ctrl, dim3(NTOK / K1_TOK), dim3(256), 0, stream,
                     x, Wc1, bc1, ch);
  hipLaunchKernelGGL(k_gate, dim3(NTOK / K2_TOK, S_SP), dim3(256), 0, stream,
                     ch, Wc2, bc2, gumbel, idx);
  hipLaunchKernelGGL(k_ffn, dim3(NTOK / 4), dim3(256), 0, stream,
                     x, W1, b1, W2T, b2, idx, out);
}

// Round 6
// 198.917 us; speedup vs baseline: 2.0195x; 2.0195x over previous
//
#include <hip/hip_runtime.h>
#include <math.h>

#define D_DIM 1024
#define H_DIM 4096
#define R_DIM 64
#define S_SP  4
#define NTOK  8192
#define CHUNK 1024   // H/S

// ---------------- K0: transpose W2 (D,H) -> W2T (H,D) ----------------
__global__ __launch_bounds__(256) void k_transpose(const float* __restrict__ W2,
                                                   float* __restrict__ W2T) {
  __shared__ float tile[64][65];
  const int hb = blockIdx.x * 64, db = blockIdx.y * 64;
  const int tx = threadIdx.x & 63, ty = threadIdx.x >> 6;
#pragma unroll
  for (int r = 0; r < 16; ++r) {
    const int d = ty * 16 + r;
    tile[tx][d] = W2[(size_t)(db + d) * H_DIM + hb + tx];
  }
  __syncthreads();
#pragma unroll
  for (int r = 0; r < 16; ++r) {
    const int h = ty * 16 + r;
    W2T[(size_t)(hb + h) * D_DIM + db + tx] = tile[h][tx];
  }
}

// ---------------- K1: ch = relu(x @ Wc1^T + bc1)  tiled GEMM ----------
// block: 32 tok x 64 r, K=1024 in 64-steps. LDS transposed tiles; each
// thread: 2 tok x 4 r register tile. All LDS reads per-lane -> full BW.
#define C_TOK 32
__global__ __launch_bounds__(256, 4) void k_ctrl(const float* __restrict__ x,
                                                 const float* __restrict__ Wc1,
                                                 const float* __restrict__ bc1,
                                                 float* __restrict__ ch) {
  __shared__ float xT[64][36];   // [k][tok], row stride 144B (16B-aligned)
  __shared__ float wT[64][68];   // [k][r],   row stride 272B
  const int tid = threadIdx.x;
  const int tok0 = blockIdx.x * C_TOK;
  const int lt = tid >> 4;          // 0..15 (loader row group)
  const int k4 = (tid & 15) * 4;    // loader k-offset
  const int tok2 = (tid >> 4) * 2;  // compute: token pair base (0..30)
  const int r4 = (tid & 15) * 4;    // compute: r quad base (0..60)
  float acc[2][4];
#pragma unroll
  for (int i = 0; i < 2; ++i)
#pragma unroll
    for (int j = 0; j < 4; ++j) acc[i][j] = 0.f;

#pragma unroll 1
  for (int k0 = 0; k0 < D_DIM; k0 += 64) {
    __syncthreads();
#pragma unroll
    for (int rep = 0; rep < 2; ++rep) {          // x: 32 rows
      const int row = lt + rep * 16;
      const float4 v = *(const float4*)(x + (size_t)(tok0 + row) * D_DIM + k0 + k4);
      xT[k4 + 0][row] = v.x; xT[k4 + 1][row] = v.y;
      xT[k4 + 2][row] = v.z; xT[k4 + 3][row] = v.w;
    }
#pragma unroll
    for (int rep = 0; rep < 4; ++rep) {          // Wc1: 64 rows
      const int row = lt + rep * 16;
      const float4 v = *(const float4*)(Wc1 + (size_t)row * D_DIM + k0 + k4);
      wT[k4 + 0][row] = v.x; wT[k4 + 1][row] = v.y;
      wT[k4 + 2][row] = v.z; wT[k4 + 3][row] = v.w;
    }
    __syncthreads();
#pragma unroll 4
    for (int k = 0; k < 64; ++k) {
      const float2 xv = *(const float2*)&xT[k][tok2];
      const float4 wv = *(const float4*)&wT[k][r4];
      const float xa[2] = {xv.x, xv.y};
      const float wa[4] = {wv.x, wv.y, wv.z, wv.w};
#pragma unroll
      for (int i = 0; i < 2; ++i)
#pragma unroll
        for (int j = 0; j < 4; ++j) acc[i][j] = fmaf(xa[i], wa[j], acc[i][j]);
    }
  }
#pragma unroll
  for (int i = 0; i < 2; ++i) {
    float4 o;
    o.x = acc[i][0] + bc1[r4 + 0];
    o.y = acc[i][1] + bc1[r4 + 1];
    o.z = acc[i][2] + bc1[r4 + 2];
    o.w = acc[i][3] + bc1[r4 + 3];
    o.x = o.x > 0.f ? o.x : 0.f; o.y = o.y > 0.f ? o.y : 0.f;
    o.z = o.z > 0.f ? o.z : 0.f; o.w = o.w > 0.f ? o.w : 0.f;
    *(float4*)(ch + (size_t)(tok0 + tok2 + i) * R_DIM + r4) = o;
  }
}

// ---- K2a: tiled GEMM logits + bias + gumbel + per-block partial argmax ----
// grid (NTOK/64, 8, 4): tile = 64 tok x 128 h, K=64. Thread: 4 tok x 8 h.
#define G_TOK 64
#define G_HB  128
__global__ __launch_bounds__(256, 3) void k_gate_a(const float* __restrict__ ch,
                                                   const float* __restrict__ Wc2,
                                                   const float* __restrict__ bc2,
                                                   const float* __restrict__ gumbel,
                                                   float2* __restrict__ part) {
  __shared__ float chT[64][68];    // [r][tok]
  __shared__ float wT[64][132];    // [r][h]
  const int tid = threadIdx.x;
  const int tok0 = blockIdx.x * G_TOK;
  const int hb = blockIdx.y;           // 0..7
  const int s  = blockIdx.z;           // 0..3
  const int h0 = hb * G_HB;            // chunk-local base
  const int lt = tid >> 4;             // 0..15
  const int r4 = (tid & 15) * 4;
  // stage chT (64 tok) and wT (128 h rows), transposed
#pragma unroll
  for (int rep = 0; rep < 4; ++rep) {
    const int row = lt + rep * 16;
    const float4 v = *(const float4*)(ch + (size_t)(tok0 + row) * R_DIM + r4);
    chT[r4 + 0][row] = v.x; chT[r4 + 1][row] = v.y;
    chT[r4 + 2][row] = v.z; chT[r4 + 3][row] = v.w;
  }
#pragma unroll
  for (int rep = 0; rep < 8; ++rep) {
    const int row = lt + rep * 16;
    const float4 v = *(const float4*)(Wc2 + (size_t)(s * CHUNK + h0 + row) * R_DIM + r4);
    wT[r4 + 0][row] = v.x; wT[r4 + 1][row] = v.y;
    wT[r4 + 2][row] = v.z; wT[r4 + 3][row] = v.w;
  }
  __syncthreads();
  const int th = tid & 15;             // h-group
  const int tt4 = (tid >> 4) * 4;      // token quad base (0..60)
  const int h8 = th * 8;               // h octet base (0..120)
  float acc[4][8];
#pragma unroll
  for (int i = 0; i < 4; ++i)
#pragma unroll
    for (int j = 0; j < 8; ++j) acc[i][j] = 0.f;
#pragma unroll 4
  for (int r = 0; r < 64; ++r) {
    const float4 cv = *(const float4*)&chT[r][tt4];
    const float4 w0 = *(const float4*)&wT[r][h8];
    const float4 w1 = *(const float4*)&wT[r][h8 + 4];
    const float ca[4] = {cv.x, cv.y, cv.z, cv.w};
    const float wa[8] = {w0.x, w0.y, w0.z, w0.w, w1.x, w1.y, w1.z, w1.w};
#pragma unroll
    for (int i = 0; i < 4; ++i)
#pragma unroll
      for (int j = 0; j < 8; ++j) acc[i][j] = fmaf(ca[i], wa[j], acc[i][j]);
  }
  // epilogue: + bias + gumbel, in-thread max over 8 h, reduce over 16 th
  const float* bp = bc2 + s * CHUNK + h0 + h8;
  const float4 b0 = *(const float4*)(bp + 0);
  const float4 b1 = *(const float4*)(bp + 4);
  const float ba[8] = {b0.x, b0.y, b0.z, b0.w, b1.x, b1.y, b1.z, b1.w};
#pragma unroll
  for (int i = 0; i < 4; ++i) {
    const int tok = tok0 + tt4 + i;
    const float* gp = gumbel + ((size_t)tok * S_SP + s) * CHUNK + h0 + h8;
    const float4 g0 = *(const float4*)(gp + 0);
    const float4 g1 = *(const float4*)(gp + 4);
    const float ga[8] = {g0.x, g0.y, g0.z, g0.w, g1.x, g1.y, g1.z, g1.w};
    float bv = -INFINITY; int bi = 0;
#pragma unroll
    for (int j = 0; j < 8; ++j) {
      const float val = acc[i][j] + ba[j] + ga[j];
      if (val > bv) { bv = val; bi = h0 + h8 + j; }
    }
#pragma unroll
    for (int o = 8; o > 0; o >>= 1) {
      const float ov = __shfl_down(bv, o, 16);
      const int   oi = __shfl_down(bi, o, 16);
      if (ov > bv || (ov == bv && oi < bi)) { bv = ov; bi = oi; }
    }
    if (th == 0)
      part[((size_t)tok * S_SP + s) * 8 + hb] = make_float2(bv, __int_as_float(bi));
  }
}

// ---- K2b: reduce 8 partials per (token,s) -> final idx ----
__global__ __launch_bounds__(256) void k_gate_b(const float2* __restrict__ part,
                                                int* __restrict__ idx) {
  const int rr = blockIdx.x * 256 + threadIdx.x;   // 0..32767 = tok*4+s
  const int s = rr & 3;
  float bv = -INFINITY; int bi = 0;
#pragma unroll
  for (int q = 0; q < 8; ++q) {
    const float2 p = part[(size_t)rr * 8 + q];
    const int pi = __float_as_int(p.y);
    if (p.x > bv || (p.x == bv && pi < bi)) { bv = p.x; bi = pi; }
  }
  idx[rr] = s * CHUNK + bi;
}

// ------- K3: wave-per-token sparse FFN (4 tokens/block, no syncthreads) ---
__global__ __launch_bounds__(256) void k_ffn(const float* __restrict__ x,
                                             const float* __restrict__ W1,
                                             const float* __restrict__ b1,
                                             const float* __restrict__ W2T,
                                             const float* __restrict__ b2,
                                             const int* __restrict__ idx,
                                             float* __restrict__ out) {
  const int tid  = threadIdx.x;
  const int lane = tid & 63;
  const int wv   = tid >> 6;
  const int token = blockIdx.x * 4 + wv;
  const int4 h4 = *(const int4*)(idx + (size_t)token * S_SP);
  const int h[4] = {h4.x, h4.y, h4.z, h4.w};
  const int d0 = lane * 16;
  const float* xp = x + (size_t)token * D_DIM + d0;
  const float4 x0 = *(const float4*)(xp + 0);
  const float4 x1 = *(const float4*)(xp + 4);
  const float4 x2 = *(const float4*)(xp + 8);
  const float4 x3 = *(const float4*)(xp + 12);
  float p[4];
#pragma unroll
  for (int s2 = 0; s2 < 4; ++s2) {
    const float* wr = W1 + (size_t)h[s2] * D_DIM + d0;
    const float4 a0 = *(const float4*)(wr + 0);
    const float4 a1 = *(const float4*)(wr + 4);
    const float4 a2 = *(const float4*)(wr + 8);
    const float4 a3 = *(const float4*)(wr + 12);
    float v = 0.f;
    v = fmaf(x0.x, a0.x, v); v = fmaf(x0.y, a0.y, v);
    v = fmaf(x0.z, a0.z, v); v = fmaf(x0.w, a0.w, v);
    v = fmaf(x1.x, a1.x, v); v = fmaf(x1.y, a1.y, v);
    v = fmaf(x1.z, a1.z, v); v = fmaf(x1.w, a1.w, v);
    v = fmaf(x2.x, a2.x, v); v = fmaf(x2.y, a2.y, v);
    v = fmaf(x2.z, a2.z, v); v = fmaf(x2.w, a2.w, v);
    v = fmaf(x3.x, a3.x, v); v = fmaf(x3.y, a3.y, v);
    v = fmaf(x3.z, a3.z, v); v = fmaf(x3.w, a3.w, v);
    p[s2] = v;
  }
#pragma unroll
  for (int s2 = 0; s2 < 4; ++s2) {
#pragma unroll
    for (int o = 1; o < 64; o <<= 1) p[s2] += __shfl_xor(p[s2], o);
  }
  float hvv[4];
#pragma unroll
  for (int s2 = 0; s2 < 4; ++s2) {
    const float v = p[s2] + b1[h[s2]];
    hvv[s2] = v > 0.f ? v : 0.f;
  }
  float4 o0 = *(const float4*)(b2 + d0 + 0);
  float4 o1 = *(const float4*)(b2 + d0 + 4);
  float4 o2 = *(const float4*)(b2 + d0 + 8);
  float4 o3 = *(const float4*)(b2 + d0 + 12);
#pragma unroll
  for (int s2 = 0; s2 < 4; ++s2) {
    const float* wr = W2T + (size_t)h[s2] * D_DIM + d0;
    const float4 a0 = *(const float4*)(wr + 0);
    const float4 a1 = *(const float4*)(wr + 4);
    const float4 a2 = *(const float4*)(wr + 8);
    const float4 a3 = *(const float4*)(wr + 12);
    const float g = hvv[s2];
    o0.x = fmaf(g, a0.x, o0.x); o0.y = fmaf(g, a0.y, o0.y);
    o0.z = fmaf(g, a0.z, o0.z); o0.w = fmaf(g, a0.w, o0.w);
    o1.x = fmaf(g, a1.x, o1.x); o1.y = fmaf(g, a1.y, o1.y);
    o1.z = fmaf(g, a1.z, o1.z); o1.w = fmaf(g, a1.w, o1.w);
    o2.x = fmaf(g, a2.x, o2.x); o2.y = fmaf(g, a2.y, o2.y);
    o2.z = fmaf(g, a2.z, o2.z); o2.w = fmaf(g, a2.w, o2.w);
    o3.x = fmaf(g, a3.x, o3.x); o3.y = fmaf(g, a3.y, o3.y);
    o3.z = fmaf(g, a3.z, o3.z); o3.w = fmaf(g, a3.w, o3.w);
  }
  float* op = out + (size_t)token * D_DIM + d0;
  *(float4*)(op + 0)  = o0;
  *(float4*)(op + 4)  = o1;
  *(float4*)(op + 8)  = o2;
  *(float4*)(op + 12) = o3;
}

extern "C" void kernel_launch(void* const* d_in, const int* in_sizes, int n_in,
                              void* d_out, int out_size, void* d_ws, size_t ws_size,
                              hipStream_t stream) {
  const float* x      = (const float*)d_in[0];
  const float* W1     = (const float*)d_in[1];
  const float* b1     = (const float*)d_in[2];
  const float* W2     = (const float*)d_in[3];
  const float* b2     = (const float*)d_in[4];
  const float* Wc1    = (const float*)d_in[5];
  const float* bc1    = (const float*)d_in[6];
  const float* Wc2    = (const float*)d_in[7];
  const float* bc2    = (const float*)d_in[8];
  const float* gumbel = (const float*)d_in[9];
  float* out = (float*)d_out;

  char* ws = (char*)d_ws;
  float*  W2T  = (float*)ws;                                    // 16.78 MB
  float*  ch   = (float*)(ws + (size_t)H_DIM * D_DIM * 4);      //  2.10 MB
  int*    idx  = (int*)(ws + (size_t)H_DIM * D_DIM * 4
                           + (size_t)NTOK * R_DIM * 4);         //  0.13 MB
  float2* part = (float2*)(ws + (size_t)H_DIM * D_DIM * 4
                              + (size_t)NTOK * R_DIM * 4
                              + (size_t)NTOK * S_SP * 4);       //  2.10 MB

  hipLaunchKernelGGL(k_transpose, dim3(H_DIM / 64, D_DIM / 64), dim3(256), 0, stream,
                     W2, W2T);
  hipLaunchKernelGGL(k_ctrl, dim3(NTOK / C_TOK), dim3(256), 0, stream,
                     x, Wc1, bc1, ch);
  hipLaunchKernelGGL(k_gate_a, dim3(NTOK / G_TOK, 8, S_SP), dim3(256), 0, stream,
                     ch, Wc2, bc2, gumbel, part);
  hipLaunchKernelGGL(k_gate_b, dim3(NTOK * S_SP / 256), dim3(256), 0, stream,
                     part, idx);
  hipLaunchKernelGGL(k_ffn, dim3(NTOK / 4), dim3(256), 0, stream,
                     x, W1, b1, W2T, b2, idx, out);
}

// Round 7
// 181.690 us; speedup vs baseline: 2.2109x; 1.0948x over previous
//
#include <hip/hip_runtime.h>
#include <math.h>

#define D_DIM 1024
#define H_DIM 4096
#define R_DIM 64
#define S_SP  4
#define NTOK  8192
#define CHUNK 1024   // H/S

// ---------------- K0: transpose W2 (D,H) -> W2T (H,D) ----------------
__global__ __launch_bounds__(256) void k_transpose(const float* __restrict__ W2,
                                                   float* __restrict__ W2T) {
  __shared__ float tile[64][65];
  const int hb = blockIdx.x * 64, db = blockIdx.y * 64;
  const int tx = threadIdx.x & 63, ty = threadIdx.x >> 6;
#pragma unroll
  for (int r = 0; r < 16; ++r) {
    const int d = ty * 16 + r;
    tile[tx][d] = W2[(size_t)(db + d) * H_DIM + hb + tx];
  }
  __syncthreads();
#pragma unroll
  for (int r = 0; r < 16; ++r) {
    const int h = ty * 16 + r;
    W2T[(size_t)(hb + h) * D_DIM + db + tx] = tile[h][tx];
  }
}

// ---------------- K1: ch = relu(x @ Wc1^T + bc1)  tiled GEMM ----------
#define C_TOK 32
__global__ __launch_bounds__(256, 4) void k_ctrl(const float* __restrict__ x,
                                                 const float* __restrict__ Wc1,
                                                 const float* __restrict__ bc1,
                                                 float* __restrict__ ch) {
  __shared__ float xT[64][36];   // [k][tok]
  __shared__ float wT[64][68];   // [k][r]
  const int tid = threadIdx.x;
  const int tok0 = blockIdx.x * C_TOK;
  const int lt = tid >> 4;          // 0..15
  const int k4 = (tid & 15) * 4;
  const int tok2 = (tid >> 4) * 2;
  const int r4 = (tid & 15) * 4;
  float acc[2][4];
#pragma unroll
  for (int i = 0; i < 2; ++i)
#pragma unroll
    for (int j = 0; j < 4; ++j) acc[i][j] = 0.f;

#pragma unroll 1
  for (int k0 = 0; k0 < D_DIM; k0 += 64) {
    __syncthreads();
#pragma unroll
    for (int rep = 0; rep < 2; ++rep) {
      const int row = lt + rep * 16;
      const float4 v = *(const float4*)(x + (size_t)(tok0 + row) * D_DIM + k0 + k4);
      xT[k4 + 0][row] = v.x; xT[k4 + 1][row] = v.y;
      xT[k4 + 2][row] = v.z; xT[k4 + 3][row] = v.w;
    }
#pragma unroll
    for (int rep = 0; rep < 4; ++rep) {
      const int row = lt + rep * 16;
      const float4 v = *(const float4*)(Wc1 + (size_t)row * D_DIM + k0 + k4);
      wT[k4 + 0][row] = v.x; wT[k4 + 1][row] = v.y;
      wT[k4 + 2][row] = v.z; wT[k4 + 3][row] = v.w;
    }
    __syncthreads();
#pragma unroll 4
    for (int k = 0; k < 64; ++k) {
      const float2 xv = *(const float2*)&xT[k][tok2];
      const float4 wv = *(const float4*)&wT[k][r4];
      const float xa[2] = {xv.x, xv.y};
      const float wa[4] = {wv.x, wv.y, wv.z, wv.w};
#pragma unroll
      for (int i = 0; i < 2; ++i)
#pragma unroll
        for (int j = 0; j < 4; ++j) acc[i][j] = fmaf(xa[i], wa[j], acc[i][j]);
    }
  }
#pragma unroll
  for (int i = 0; i < 2; ++i) {
    float4 o;
    o.x = acc[i][0] + bc1[r4 + 0];
    o.y = acc[i][1] + bc1[r4 + 1];
    o.z = acc[i][2] + bc1[r4 + 2];
    o.w = acc[i][3] + bc1[r4 + 3];
    o.x = o.x > 0.f ? o.x : 0.f; o.y = o.y > 0.f ? o.y : 0.f;
    o.z = o.z > 0.f ? o.z : 0.f; o.w = o.w > 0.f ? o.w : 0.f;
    *(float4*)(ch + (size_t)(tok0 + tok2 + i) * R_DIM + r4) = o;
  }
}

// ---- K2a: 128tok x 128h tile, K=64 in two 32-staged phases ----
// Thread: 8 tok x 8 h (two interleaved float4 h-chunks: th*4 and 64+th*4
// -> 2-way bank aliasing only). FMA:LDS = 128:32 cyc -> FMA-bound.
#define G_TOK 128
#define G_HB  128
__global__ __launch_bounds__(256, 4) void k_gate_a(const float* __restrict__ ch,
                                                   const float* __restrict__ Wc2,
                                                   const float* __restrict__ bc2,
                                                   const float* __restrict__ gumbel,
                                                   float2* __restrict__ part) {
  __shared__ float chT[32][132];   // [r][tok]
  __shared__ float wT[32][132];    // [r][h]
  const int tid = threadIdx.x;
  const int tok0 = blockIdx.x * G_TOK;
  const int hb = blockIdx.y;           // 0..7
  const int s  = blockIdx.z;           // 0..3
  const int h0 = hb * G_HB;
  const int th  = tid & 15;
  const int tt8 = (tid >> 4) * 8;      // token octet base
  const int th4 = th * 4;              // h chunk A base; chunk B = 64+th4
  const int lrow = tid >> 3;           // 0..31 (loader)
  const int lk4  = (tid & 7) * 4;      // 0..28
  float acc[8][8];
#pragma unroll
  for (int i = 0; i < 8; ++i)
#pragma unroll
    for (int j = 0; j < 8; ++j) acc[i][j] = 0.f;

#pragma unroll 1
  for (int p = 0; p < 2; ++p) {
    __syncthreads();
#pragma unroll
    for (int rep = 0; rep < 4; ++rep) {          // ch: 128 rows x 32 k
      const int row = lrow + rep * 32;
      const float4 v = *(const float4*)(ch + (size_t)(tok0 + row) * R_DIM + p * 32 + lk4);
      chT[lk4 + 0][row] = v.x; chT[lk4 + 1][row] = v.y;
      chT[lk4 + 2][row] = v.z; chT[lk4 + 3][row] = v.w;
    }
#pragma unroll
    for (int rep = 0; rep < 4; ++rep) {          // Wc2: 128 rows x 32 k
      const int row = lrow + rep * 32;
      const float4 v = *(const float4*)(Wc2 + (size_t)(s * CHUNK + h0 + row) * R_DIM + p * 32 + lk4);
      wT[lk4 + 0][row] = v.x; wT[lk4 + 1][row] = v.y;
      wT[lk4 + 2][row] = v.z; wT[lk4 + 3][row] = v.w;
    }
    __syncthreads();
#pragma unroll 2
    for (int k = 0; k < 32; ++k) {
      const float4 c0 = *(const float4*)&chT[k][tt8];
      const float4 c1 = *(const float4*)&chT[k][tt8 + 4];
      const float4 w0 = *(const float4*)&wT[k][th4];
      const float4 w1 = *(const float4*)&wT[k][64 + th4];
      const float ca[8] = {c0.x, c0.y, c0.z, c0.w, c1.x, c1.y, c1.z, c1.w};
      const float wa[8] = {w0.x, w0.y, w0.z, w0.w, w1.x, w1.y, w1.z, w1.w};
#pragma unroll
      for (int i = 0; i < 8; ++i)
#pragma unroll
        for (int j = 0; j < 8; ++j) acc[i][j] = fmaf(ca[i], wa[j], acc[i][j]);
    }
  }
  // epilogue: + bias + gumbel, per-token partial argmax over this 128-h tile
  const float4 b0 = *(const float4*)(bc2 + s * CHUNK + h0 + th4);
  const float4 b1 = *(const float4*)(bc2 + s * CHUNK + h0 + 64 + th4);
  const float ba[8] = {b0.x, b0.y, b0.z, b0.w, b1.x, b1.y, b1.z, b1.w};
#pragma unroll
  for (int i = 0; i < 8; ++i) {
    const int tok = tok0 + tt8 + i;
    const float* gp = gumbel + ((size_t)tok * S_SP + s) * CHUNK + h0;
    const float4 g0 = *(const float4*)(gp + th4);
    const float4 g1 = *(const float4*)(gp + 64 + th4);
    const float ga[8] = {g0.x, g0.y, g0.z, g0.w, g1.x, g1.y, g1.z, g1.w};
    float bv = -INFINITY; int bi = 0;
#pragma unroll
    for (int j = 0; j < 8; ++j) {
      const int hl = (j < 4) ? (th4 + j) : (64 + th4 + j - 4);
      const float val = acc[i][j] + ba[j] + ga[j];
      if (val > bv) { bv = val; bi = hl; }   // ascending hl within thread
    }
#pragma unroll
    for (int o = 8; o > 0; o >>= 1) {
      const float ov = __shfl_down(bv, o, 16);
      const int   oi = __shfl_down(bi, o, 16);
      if (ov > bv || (ov == bv && oi < bi)) { bv = ov; bi = oi; }
    }
    if (th == 0)
      part[((size_t)tok * S_SP + s) * 8 + hb] = make_float2(bv, __int_as_float(h0 + bi));
  }
}

// ------- K3: wave-per-token sparse FFN; folds the partial-argmax reduce ---
__global__ __launch_bounds__(256) void k_ffn(const float* __restrict__ x,
                                             const float* __restrict__ W1,
                                             const float* __restrict__ b1,
                                             const float* __restrict__ W2T,
                                             const float* __restrict__ b2,
                                             const float2* __restrict__ part,
                                             float* __restrict__ out) {
  const int tid  = threadIdx.x;
  const int lane = tid & 63;
  const int wv   = tid >> 6;
  const int token = blockIdx.x * 4 + wv;
  // final argmax: lanes 0..31 reduce 8 partials per s (width-8 groups)
  float bv = -INFINITY; int bi = 0;
  {
    const int ss = (lane >> 3) & 3;
    const int q  = lane & 7;
    if (lane < 32) {
      const float2 p = part[((size_t)token * S_SP + ss) * 8 + q];
      bv = p.x; bi = __float_as_int(p.y);
    }
#pragma unroll
    for (int o = 4; o > 0; o >>= 1) {
      const float ov = __shfl_down(bv, o, 8);
      const int   oi = __shfl_down(bi, o, 8);
      if (ov > bv || (ov == bv && oi < bi)) { bv = ov; bi = oi; }
    }
  }
  int h[4];
#pragma unroll
  for (int s2 = 0; s2 < 4; ++s2)
    h[s2] = s2 * CHUNK + __shfl(bi, s2 * 8);

  const int d0 = lane * 16;
  const float* xp = x + (size_t)token * D_DIM + d0;
  const float4 x0 = *(const float4*)(xp + 0);
  const float4 x1 = *(const float4*)(xp + 4);
  const float4 x2 = *(const float4*)(xp + 8);
  const float4 x3 = *(const float4*)(xp + 12);
  float p[4];
#pragma unroll
  for (int s2 = 0; s2 < 4; ++s2) {
    const float* wr = W1 + (size_t)h[s2] * D_DIM + d0;
    const float4 a0 = *(const float4*)(wr + 0);
    const float4 a1 = *(const float4*)(wr + 4);
    const float4 a2 = *(const float4*)(wr + 8);
    const float4 a3 = *(const float4*)(wr + 12);
    float v = 0.f;
    v = fmaf(x0.x, a0.x, v); v = fmaf(x0.y, a0.y, v);
    v = fmaf(x0.z, a0.z, v); v = fmaf(x0.w, a0.w, v);
    v = fmaf(x1.x, a1.x, v); v = fmaf(x1.y, a1.y, v);
    v = fmaf(x1.z, a1.z, v); v = fmaf(x1.w, a1.w, v);
    v = fmaf(x2.x, a2.x, v); v = fmaf(x2.y, a2.y, v);
    v = fmaf(x2.z, a2.z, v); v = fmaf(x2.w, a2.w, v);
    v = fmaf(x3.x, a3.x, v); v = fmaf(x3.y, a3.y, v);
    v = fmaf(x3.z, a3.z, v); v = fmaf(x3.w, a3.w, v);
    p[s2] = v;
  }
#pragma unroll
  for (int s2 = 0; s2 < 4; ++s2) {
#pragma unroll
    for (int o = 1; o < 64; o <<= 1) p[s2] += __shfl_xor(p[s2], o);
  }
  float hvv[4];
#pragma unroll
  for (int s2 = 0; s2 < 4; ++s2) {
    const float v = p[s2] + b1[h[s2]];
    hvv[s2] = v > 0.f ? v : 0.f;
  }
  float4 o0 = *(const float4*)(b2 + d0 + 0);
  float4 o1 = *(const float4*)(b2 + d0 + 4);
  float4 o2 = *(const float4*)(b2 + d0 + 8);
  float4 o3 = *(const float4*)(b2 + d0 + 12);
#pragma unroll
  for (int s2 = 0; s2 < 4; ++s2) {
    const float* wr = W2T + (size_t)h[s2] * D_DIM + d0;
    const float4 a0 = *(const float4*)(wr + 0);
    const float4 a1 = *(const float4*)(wr + 4);
    const float4 a2 = *(const float4*)(wr + 8);
    const float4 a3 = *(const float4*)(wr + 12);
    const float g = hvv[s2];
    o0.x = fmaf(g, a0.x, o0.x); o0.y = fmaf(g, a0.y, o0.y);
    o0.z = fmaf(g, a0.z, o0.z); o0.w = fmaf(g, a0.w, o0.w);
    o1.x = fmaf(g, a1.x, o1.x); o1.y = fmaf(g, a1.y, o1.y);
    o1.z = fmaf(g, a1.z, o1.z); o1.w = fmaf(g, a1.w, o1.w);
    o2.x = fmaf(g, a2.x, o2.x); o2.y = fmaf(g, a2.y, o2.y);
    o2.z = fmaf(g, a2.z, o2.z); o2.w = fmaf(g, a2.w, o2.w);
    o3.x = fmaf(g, a3.x, o3.x); o3.y = fmaf(g, a3.y, o3.y);
    o3.z = fmaf(g, a3.z, o3.z); o3.w = fmaf(g, a3.w, o3.w);
  }
  float* op = out + (size_t)token * D_DIM + d0;
  *(float4*)(op + 0)  = o0;
  *(float4*)(op + 4)  = o1;
  *(float4*)(op + 8)  = o2;
  *(float4*)(op + 12) = o3;
}

extern "C" void kernel_launch(void* const* d_in, const int* in_sizes, int n_in,
                              void* d_out, int out_size, void* d_ws, size_t ws_size,
                              hipStream_t stream) {
  const float* x      = (const float*)d_in[0];
  const float* W1     = (const float*)d_in[1];
  const float* b1     = (const float*)d_in[2];
  const float* W2     = (const float*)d_in[3];
  const float* b2     = (const float*)d_in[4];
  const float* Wc1    = (const float*)d_in[5];
  const float* bc1    = (const float*)d_in[6];
  const float* Wc2    = (const float*)d_in[7];
  const float* bc2    = (const float*)d_in[8];
  const float* gumbel = (const float*)d_in[9];
  float* out = (float*)d_out;

  char* ws = (char*)d_ws;
  float*  W2T  = (float*)ws;                                    // 16.78 MB
  float*  ch   = (float*)(ws + (size_t)H_DIM * D_DIM * 4);      //  2.10 MB
  float2* part = (float2*)(ws + (size_t)H_DIM * D_DIM * 4
                              + (size_t)NTOK * R_DIM * 4);      //  2.10 MB

  hipLaunchKernelGGL(k_transpose, dim3(H_DIM / 64, D_DIM / 64), dim3(256), 0, stream,
                     W2, W2T);
  hipLaunchKernelGGL(k_ctrl, dim3(NTOK / C_TOK), dim3(256), 0, stream,
                     x, Wc1, bc1, ch);
  hipLaunchKernelGGL(k_gate_a, dim3(NTOK / G_TOK, CHUNK / G_HB, S_SP), dim3(256), 0, stream,
                     ch, Wc2, bc2, gumbel, part);
  hipLaunchKernelGGL(k_ffn, dim3(NTOK / 4), dim3(256), 0, stream,
                     x, W1, b1, W2T, b2, part, out);
}